// Round 5
// baseline (323.189 us; speedup 1.0000x reference)
//
#include <hip/hip_runtime.h>
#include <hip/hip_bf16.h>

// ModulatedConv2d (StyleGAN2): B=16, Cin=Cout=128, K=3, H=W=128, STYLE=512
// R8: software-pipelined A staging (T3 2-phase schedule, m248 pattern).
//     A tile double-buffered (2x16 KB); stage(T+1) issued at the top of
//     tap T's segment so the vmcnt(0) drain at the closing barrier lands
//     after T's MFMA work, not before it. One barrier per tap (25/block
//     vs R7's 37). Input row in a single 16 KB slot, rewritten per ky in a
//     short write-segment (loads exposed once per ky, as in R7's upfront).
//     LDS 48 KB -> 3 blocks/CU. No cross-barrier register holding.

typedef __attribute__((ext_vector_type(8))) short short8;
typedef __attribute__((ext_vector_type(4))) float f32x4;

#define CONV_SCALE 0.029462782549439483f /* 1/sqrt(128*9) */
#define LIN_SCALE 0.04419417382415922f   /* 1/sqrt(512) */

__device__ __forceinline__ void async16(unsigned short* lds, const unsigned short* g) {
  __builtin_amdgcn_global_load_lds((const __attribute__((address_space(1))) void*)g,
                                   (__attribute__((address_space(3))) void*)lds, 16, 0, 0);
}

__device__ __forceinline__ unsigned int pack2bf(float a, float b) {
  unsigned short ha = __builtin_bit_cast(unsigned short, __float2bfloat16(a));
  unsigned short hb = __builtin_bit_cast(unsigned short, __float2bfloat16(b));
  return (unsigned int)ha | ((unsigned int)hb << 16);
}

// s[b][cin] = sum_d style[b,d] * mod_w[cin,d] * LIN_SCALE + mod_b[cin]
__global__ void style_kernel(const float* __restrict__ style, const float* __restrict__ mod_w,
                             const float* __restrict__ mod_b, float* __restrict__ s_ws) {
  const int gw = blockIdx.x * 4 + (threadIdx.x >> 6);  // global wave 0..2047
  const int b = gw >> 7, cin = gw & 127, lane = threadIdx.x & 63;
  const float4 s0 = *(const float4*)(style + (size_t)b * 512 + lane * 4);
  const float4 s1 = *(const float4*)(style + (size_t)b * 512 + 256 + lane * 4);
  const float4 w0 = *(const float4*)(mod_w + (size_t)cin * 512 + lane * 4);
  const float4 w1 = *(const float4*)(mod_w + (size_t)cin * 512 + 256 + lane * 4);
  float acc = s0.x * w0.x + s0.y * w0.y + s0.z * w0.z + s0.w * w0.w +
              s1.x * w1.x + s1.y * w1.y + s1.z * w1.z + s1.w * w1.w;
#pragma unroll
  for (int off = 32; off; off >>= 1) acc += __shfl_xor(acc, off);
  if (lane == 0) s_ws[b * 128 + cin] = acc * LIN_SCALE + mod_b[cin];
}

// one block per (b, cout): wmod = CONV_SCALE*weight*s ; demod = rsqrt(sum wmod^2 + 1e-8)
// write bf16 w_ws[b][ky*3+kx][cout][cin]  (cin fastest, for A-tile staging)
__global__ void modw_kernel(const float* __restrict__ weight, const float* __restrict__ s_ws,
                            unsigned short* __restrict__ w_ws) {
  const int bid = blockIdx.x;
  const int b = bid >> 7, cout = bid & 127;
  const int cin = threadIdx.x;
  const float sv = s_ws[b * 128 + cin] * CONV_SCALE;
  const float* wp = weight + ((size_t)cout * 128 + cin) * 9;
  float v[9];
  float ss = 0.f;
#pragma unroll
  for (int j = 0; j < 9; ++j) { v[j] = wp[j] * sv; ss += v[j] * v[j]; }
#pragma unroll
  for (int off = 32; off; off >>= 1) ss += __shfl_down(ss, off);
  __shared__ float red[2];
  if ((threadIdx.x & 63) == 0) red[threadIdx.x >> 6] = ss;
  __syncthreads();
  const float dem = rsqrtf(red[0] + red[1] + 1e-8f);
#pragma unroll
  for (int j = 0; j < 9; ++j) {
    __hip_bfloat16 h = __float2bfloat16(v[j] * dem);
    w_ws[(((size_t)b * 9 + j) * 128 + cout) * 128 + cin] =
        __builtin_bit_cast(unsigned short, h);
  }
}

// Transpose one input row (64 cin of this half, 128 x) fp32 NCHW -> bf16
// xr slot [x 0..127][64 cin], 16B cin-groups XOR-swizzled by (x&7), the
// 8B half-group placed at +((tcq&1)*4). Conflict-free 8B writes (R5-R7).
__device__ __forceinline__ void transpose_row(const float* __restrict__ xb, int c0, int yy,
                                              unsigned short* __restrict__ dst, int tid) {
  const int tcq = tid & 15, t4 = tid >> 4;  // cin-quad 0..15, x-quad-base 0..15
  if (yy < 0 || yy > 127) {
    const uint2 z = {0u, 0u};
#pragma unroll
    for (int xi = 0; xi < 2; ++xi)
#pragma unroll
      for (int i = 0; i < 4; ++i) {
        const int xp = (xi * 16 + t4) * 4 + i;
        *(uint2*)(dst + xp * 64 + (((tcq >> 1) ^ (xp & 7)) << 3) + ((tcq & 1) << 2)) = z;
      }
    return;
  }
  const float* row = xb + (size_t)(c0 + tcq * 4) * 16384 + (size_t)yy * 128;
#pragma unroll
  for (int xi = 0; xi < 2; ++xi) {
    const int xq = xi * 16 + t4;
    float4 f[4];
#pragma unroll
    for (int j = 0; j < 4; ++j) f[j] = *(const float4*)(row + (size_t)j * 16384 + xq * 4);
#pragma unroll
    for (int i = 0; i < 4; ++i) {
      const int xp = xq * 4 + i;
      uint2 col;
      col.x = pack2bf(((const float*)&f[0])[i], ((const float*)&f[1])[i]);
      col.y = pack2bf(((const float*)&f[2])[i], ((const float*)&f[3])[i]);
      *(uint2*)(dst + xp * 64 + (((tcq >> 1) ^ (xp & 7)) << 3) + ((tcq & 1) << 2)) = col;
    }
  }
}

// one block per (b, y): out[b][0..127][y][0..127] = sum_{ky,kx,cin} w'*x
// 128x128 tile, 4 waves 2x2, each wave 4x4 of 16x16x32 bf16 MFMA.
// Tap order T = h*9 + ky*3 + kx (h = cin-half). Per tap segment:
//   [stage A(T+1) -> lA[par^1]] ; compute T from lA[par], xr ; barrier.
// The closing barrier's vmcnt(0) drain covers stage(T+1), which by then
// has had a full MFMA phase in flight. Row rewrite happens in a short
// write-segment per (h,ky) between the previous closing barrier and a
// visibility barrier.
__global__ __launch_bounds__(256, 3) void conv_kernel(const float* __restrict__ x,
                                                      const unsigned short* __restrict__ wws,
                                                      float* __restrict__ out) {
  __shared__ unsigned short xr[128 * 64];     // 16 KB: current input row
  __shared__ unsigned short lA[2][128 * 64];  // 32 KB: A tile double buffer

  const int tid = threadIdx.x;
  // XCD-aware swizzle: XCD gets contiguous (b,y) range -> weight + row L2 reuse.
  const int bid = (blockIdx.x & 7) * 256 + (blockIdx.x >> 3);
  const int b = bid >> 7, y = bid & 127;
  const int lane = tid & 63, w = tid >> 6;
  const int wm = w & 1, wn = w >> 1;
  const int l15 = lane & 15, q = lane >> 4;

  f32x4 acc[4][4];
#pragma unroll
  for (int i = 0; i < 4; ++i)
#pragma unroll
    for (int t = 0; t < 4; ++t) acc[i][t] = (f32x4){0.f, 0.f, 0.f, 0.f};

  const float* xb = x + (size_t)b * (128 * 16384);
  const unsigned short* wb = wws + (size_t)b * 9 * 128 * 128;

  // A staging: 4 async16/thread, pre-swizzled global source, linear LDS dest
  const int mbase = tid >> 3;  // 0..31
  const int goff = (((tid & 7) ^ ((tid >> 3) & 7)) << 3);
  const int eoff = tid * 8;

  int nt[4];
#pragma unroll
  for (int t = 0; t < 4; ++t) nt[t] = wn * 64 + t * 16 + l15;  // x coord

  const short8 zero8 = {0, 0, 0, 0, 0, 0, 0, 0};

  // prologue: stage A for tap 0 (j3=0, c0=0) into buffer 0; drains at the
  // first write-segment's barrier (overlapped with the transpose loads).
#pragma unroll
  for (int p = 0; p < 4; ++p)
    async16(lA[0] + p * 2048 + eoff, wb + p * 4096 + mbase * 128 + goff);

  int par = 0;
  for (int h = 0; h < 2; ++h) {
    const int c0 = h << 6;
    for (int ky = 0; ky < 3; ++ky) {
      // ---- write segment: row y+ky-1 of this half into xr ----
      // previous taps' readers of xr finished at the last closing barrier
      transpose_row(xb, c0, y + ky - 1, xr, tid);
      __syncthreads();  // xr visible (also drains pending stage / prologue)
      for (int kx = 0; kx < 3; ++kx) {
        // stage A for the next tap into the other buffer
        const bool last = (h == 1) && (ky == 2) && (kx == 2);
        if (!last) {
          const int nkx = (kx < 2) ? kx + 1 : 0;
          const int nky = (kx < 2) ? ky : ((ky < 2) ? ky + 1 : 0);
          const int nc0 = (kx == 2 && ky == 2) ? 64 : c0;
          const int nj3 = nky * 3 + nkx;
          unsigned short* dst = lA[par ^ 1];
#pragma unroll
          for (int p = 0; p < 4; ++p)
            async16(dst + p * 2048 + eoff, wb + nj3 * 16384 + nc0 + p * 4096 + mbase * 128 + goff);
        }
        // compute tap (h, ky, kx) from lA[par] and xr
        const unsigned short* Ab = lA[par];
        int xcb[4];
#pragma unroll
        for (int t = 0; t < 4; ++t) xcb[t] = nt[t] + (kx - 1);
        const bool lo = (xcb[0] < 0);    // kx==0, wn==0, l15==0 lanes
        const bool hi = (xcb[3] > 127);  // kx==2, wn==1, l15==15 lanes
        if (lo) xcb[0] = 0;
        if (hi) xcb[3] = 127;
#pragma unroll
        for (int s = 0; s < 2; ++s) {
          const int s4q = s * 4 + q;
          const int axor = ((s4q ^ (l15 & 7)) << 3);
          short8 af[4], bf[4];
#pragma unroll
          for (int i = 0; i < 4; ++i)
            af[i] = *(const short8*)(Ab + (wm * 64 + i * 16 + l15) * 64 + axor);
#pragma unroll
          for (int t = 0; t < 4; ++t)
            bf[t] = *(const short8*)(xr + xcb[t] * 64 + ((s4q ^ (xcb[t] & 7)) << 3));
          if (lo) bf[0] = zero8;
          if (hi) bf[3] = zero8;
#pragma unroll
          for (int i = 0; i < 4; ++i)
#pragma unroll
            for (int t = 0; t < 4; ++t)
              acc[i][t] = __builtin_amdgcn_mfma_f32_16x16x32_bf16(af[i], bf[t], acc[i][t], 0, 0, 0);
        }
        __syncthreads();  // readers done; drains stage(T+1)
        par ^= 1;
      }
    }
  }

  // C/D layout: col(pixel) = lane&15, row(cout) = (lane>>4)*4 + reg
  float* ob = out + ((size_t)b * 128 * 128 + y) * 128;
#pragma unroll
  for (int i = 0; i < 4; ++i) {
    const int coutb = wm * 64 + i * 16 + q * 4;
#pragma unroll
    for (int rr = 0; rr < 4; ++rr) {
      float* orow = ob + (size_t)(coutb + rr) * (128 * 128);
#pragma unroll
      for (int t = 0; t < 4; ++t) orow[wn * 64 + t * 16 + l15] = acc[i][t][rr];
    }
  }
}

extern "C" void kernel_launch(void* const* d_in, const int* in_sizes, int n_in,
                              void* d_out, int out_size, void* d_ws, size_t ws_size,
                              hipStream_t stream) {
  const float* x = (const float*)d_in[0];
  const float* style = (const float*)d_in[1];
  const float* weight = (const float*)d_in[2];
  const float* mod_w = (const float*)d_in[3];
  const float* mod_b = (const float*)d_in[4];
  float* out = (float*)d_out;

  char* ws = (char*)d_ws;
  float* s_ws = (float*)ws;                             // 8 KB
  unsigned short* w_ws = (unsigned short*)(ws + 8192);  // 4.7 MB

  style_kernel<<<512, 256, 0, stream>>>(style, mod_w, mod_b, s_ws);
  modw_kernel<<<16 * 128, 128, 0, stream>>>(weight, s_ws, w_ws);
  conv_kernel<<<16 * 128, 256, 0, stream>>>(x, w_ws, out);
}